// Round 6
// baseline (126.332 us; speedup 1.0000x reference)
//
#include <hip/hip_runtime.h>
#include <hip/hip_fp16.h>

typedef _Float16 f16;
typedef __attribute__((ext_vector_type(8))) _Float16 half8;
typedef __attribute__((ext_vector_type(2))) __fp16 fp16x2_native;
typedef __attribute__((ext_vector_type(4))) float floatx4;
typedef __attribute__((ext_vector_type(16))) float f32x16;
typedef __attribute__((ext_vector_type(4))) unsigned uint4v;
typedef __attribute__((ext_vector_type(2))) unsigned uint2v;

static constexpr int DIM = 1024;
static constexpr int SEQ = 2048;
static constexpr int DH = 64;
static constexpr int MTOT = 4096;  // BATCH * SEQ

__device__ __forceinline__ float fexp2(float x) {
#if __has_builtin(__builtin_amdgcn_exp2f)
  return __builtin_amdgcn_exp2f(x);
#else
  return exp2f(x);
#endif
}

__device__ __forceinline__ unsigned pkrtz(float a, float b) {
  fp16x2_native h = __builtin_amdgcn_cvt_pkrtz(a, b);
  return __builtin_bit_cast(unsigned, h);
}

__device__ __forceinline__ void pl32swap(unsigned& a, unsigned& b) {
#if __has_builtin(__builtin_amdgcn_permlane32_swap)
  uint2v r = __builtin_amdgcn_permlane32_swap(a, b, false, false);
  a = r.x;
  b = r.y;
#else
  asm volatile("v_permlane32_swap_b32 %0, %1" : "+v"(a), "+v"(b));
#endif
}

// async global->LDS 16B
__device__ __forceinline__ void gll16(const f16* g, f16* l) {
  auto gp = (__attribute__((address_space(1))) unsigned*)(uintptr_t)(const void*)g;
  auto lp = (__attribute__((address_space(3))) unsigned*)(uintptr_t)(void*)l;
  __builtin_amdgcn_global_load_lds(gp, lp, 16, 0, 0);
}

// ---- weight transpose + fp16 convert: wt[z][n][k] = W_z[k][n] ----
__global__ __launch_bounds__(256) void k_transpose(
    const float* __restrict__ Wq, const float* __restrict__ Wk,
    const float* __restrict__ Wv, const float* __restrict__ Wo,
    f16* __restrict__ wt)
{
  __shared__ float tile[32][33];
  const int z = blockIdx.z;
  const float* W = (z == 0) ? Wq : (z == 1) ? Wk : (z == 2) ? Wv : Wo;
  f16* out = wt + (size_t)z * DIM * DIM;
  const int tx = threadIdx.x, ty = threadIdx.y;
  const int x0 = blockIdx.x * 32, y0 = blockIdx.y * 32;
#pragma unroll
  for (int i = 0; i < 4; ++i)
    tile[ty + i * 8][tx] = W[(size_t)(y0 + ty + i * 8) * DIM + (x0 + tx)];
  __syncthreads();
#pragma unroll
  for (int i = 0; i < 4; ++i)
    out[(size_t)(x0 + ty + i * 8) * DIM + (y0 + tx)] = (f16)tile[tx][ty + i * 8];
}

// ---- x fp32 -> fp16 ----
__global__ __launch_bounds__(256) void k_xcast(
    const float* __restrict__ in, f16* __restrict__ out)
{
  const int i = blockIdx.x * 256 + threadIdx.x;
  const float4* p = (const float4*)in;
  float4 a = p[2 * i], b = p[2 * i + 1];
  half8 h = {(f16)a.x, (f16)a.y, (f16)a.z, (f16)a.w,
             (f16)b.x, (f16)b.y, (f16)b.z, (f16)b.w};
  *(half8*)(out + (size_t)i * 8) = h;
}

// ---- V^T pre-transpose: vt[bh][d][n] = V[b][n][h*64+d] ----
__global__ __launch_bounds__(256) void k_vtrans(
    const f16* __restrict__ vh, f16* __restrict__ vt)
{
  __shared__ f16 T[64][72];
  const int tid = threadIdx.x;
  const int nt = blockIdx.x, bh = blockIdx.y;
  const int b = bh >> 4, h = bh & 15;
  const int n0 = nt * 64;
  const f16* src = vh + (size_t)b * SEQ * DIM + (size_t)h * DH;
#pragma unroll
  for (int i = 0; i < 2; ++i) {
    const int n = (tid >> 3) + i * 32;
    const int cc = tid & 7;
    half8 v = *(const half8*)(src + (size_t)(n0 + n) * DIM + cc * 8);
#pragma unroll
    for (int j = 0; j < 8; ++j) T[cc * 8 + j][n] = v[j];
  }
  __syncthreads();
  f16* dst = vt + (size_t)bh * DH * SEQ;
#pragma unroll
  for (int i = 0; i < 2; ++i) {
    const int d = (tid >> 3) + i * 32;
    const int cc = tid & 7;
    half8 w = *(const half8*)&T[d][cc * 8];
    *(half8*)(dst + (size_t)d * SEQ + n0 + cc * 8) = w;
  }
}

// ---- per-(b,h) max row-norm of K -> kmaxu[32] (uint-ordered fp32 >= 0) ----
__global__ __launch_bounds__(256) void k_knorm(
    const f16* __restrict__ kh, unsigned* __restrict__ kmaxu)
{
  __shared__ unsigned lm[16];
  const int t = blockIdx.x * 256 + threadIdx.x;
  const int macro = t >> 4;     // b*2048 + n   (block spans 16 macros, same b)
  const int h = t & 15;
  const f16* row = kh + (size_t)macro * DIM + h * DH;
  float s = 0.f;
#pragma unroll
  for (int i = 0; i < 8; ++i) {
    half8 v = *(const half8*)(row + i * 8);
#pragma unroll
    for (int j = 0; j < 8; ++j) {
      const float f = (float)v[j];
      s = fmaf(f, f, s);
    }
  }
  const float nrm = sqrtf(s);
  if (threadIdx.x < 16) lm[threadIdx.x] = 0u;
  __syncthreads();
  atomicMax(&lm[h], __float_as_uint(nrm));
  __syncthreads();
  if (threadIdx.x < 16) {
    const int b = macro >> 11;
    atomicMax(&kmaxu[b * 16 + threadIdx.x], lm[threadIdx.x]);
  }
}

// ---- fp16 GEMM, 128x128 tile, BK=32, gll double-buffer, 1 barrier/step ----
template <bool OUT_F32>
__global__ __launch_bounds__(256) void k_gemm2(
    const f16* __restrict__ A, const f16* __restrict__ BT,
    void* __restrict__ Cptr, const float* __restrict__ bias,
    int M, int N, int K, size_t bt_zstride, size_t c_zstride)
{
  __shared__ f16 SB[2][8192];

  const int tid = threadIdx.x;
  const int lane = tid & 63;
  const int wid = tid >> 6;
  const int wr = (wid >> 1) * 64, wc = (wid & 1) * 64;
  const int li = lane & 15, lg = lane >> 4;

  const f16* BTz = BT + (size_t)blockIdx.z * bt_zstride;
  const int row0 = blockIdx.x * 128, col0 = blockIdx.y * 128;

  const int c0 = tid;
  const int c1 = 256 + tid;
  const f16* a0 = A + (size_t)(row0 + (c0 >> 2)) * K + (c0 & 3) * 8;
  const f16* a1 = A + (size_t)(row0 + (c1 >> 2)) * K + (c1 & 3) * 8;
  const f16* b0 = BTz + (size_t)(col0 + (c0 >> 2)) * K + (c0 & 3) * 8;
  const f16* b1 = BTz + (size_t)(col0 + (c1 >> 2)) * K + (c1 & 3) * 8;
  const int da0 = wid * 512, da1 = 2048 + wid * 512;

  const floatx4 zero4 = {0.f, 0.f, 0.f, 0.f};
  floatx4 acc[4][4];
#pragma unroll
  for (int m = 0; m < 4; ++m)
#pragma unroll
    for (int n = 0; n < 4; ++n) acc[m][n] = zero4;

  auto issue = [&](int buf) {
    gll16(a0, &SB[buf][da0]);
    gll16(a1, &SB[buf][da1]);
    gll16(b0, &SB[buf][4096 + da0]);
    gll16(b1, &SB[buf][4096 + da1]);
    a0 += 32; a1 += 32; b0 += 32; b1 += 32;
  };

  const int nstep = K >> 5;
  issue(0);

  auto step = [&](int buf, int t) {
    asm volatile("s_waitcnt vmcnt(0)" ::: "memory");
    __builtin_amdgcn_s_barrier();
    asm volatile("" ::: "memory");
    if (t + 1 < nstep) issue(buf ^ 1);
    const f16* As = &SB[buf][0];
    const f16* Bs = &SB[buf][4096];
    half8 af[4], bf[4];
#pragma unroll
    for (int m = 0; m < 4; ++m)
      af[m] = *(const half8*)&As[(wr + m * 16 + li) * 32 + lg * 8];
#pragma unroll
    for (int n = 0; n < 4; ++n)
      bf[n] = *(const half8*)&Bs[(wc + n * 16 + li) * 32 + lg * 8];
#pragma unroll
    for (int m = 0; m < 4; ++m)
#pragma unroll
      for (int n = 0; n < 4; ++n)
        acc[m][n] = __builtin_amdgcn_mfma_f32_16x16x32_f16(af[m], bf[n], acc[m][n], 0, 0, 0);
  };

  for (int t2 = 0; t2 < nstep; t2 += 2) {
    step(0, t2);
    step(1, t2 + 1);
  }

#pragma unroll
  for (int m = 0; m < 4; ++m)
#pragma unroll
    for (int n = 0; n < 4; ++n)
#pragma unroll
      for (int r = 0; r < 4; ++r) {
        const int row = row0 + wr + m * 16 + lg * 4 + r;
        const int col = col0 + wc + n * 16 + li;
        if constexpr (OUT_F32) {
          float* C = (float*)Cptr + (size_t)blockIdx.z * c_zstride;
          C[(size_t)row * N + col] = acc[m][n][r] + bias[col];
        } else {
          f16* C = (f16*)Cptr + (size_t)blockIdx.z * c_zstride;
          C[(size_t)row * N + col] = (f16)acc[m][n][r];
        }
      }
}

// ---- flash attention v5: static softmax bound (no max tracking),
//      8 waves, intra-block KV split, gll double-buffer ----
__global__ __launch_bounds__(512) void k_attn5(
    const f16* __restrict__ qh, const f16* __restrict__ kh,
    const f16* __restrict__ vt, const unsigned* __restrict__ kmaxu,
    f16* __restrict__ oh)
{
  __shared__ f16 KV[2][16384];   // [buf][K0|V0|K1|V1] 4096 f16 each, swizzled
  __shared__ float bc[8][32];
  __shared__ float Ll[4][32], W0[4][32], W1[4][32];

  const int tid = threadIdx.x;
  const int lane = tid & 63;
  const int wid = tid >> 6;   // 0..7
  const int g = wid >> 2;     // kv-half group
  const int sub = wid & 3;    // q-subtile
  const int col = lane & 31;
  const int hi = lane >> 5;

  // XCD-bijective swizzle: 512 blocks, XCD owns 4 consecutive bh
  const int id = blockIdx.x;
  const int xcd = id & 7;
  const int j = id >> 3;
  const int bh = xcd * 4 + (j >> 4);
  const int qi = j & 15;
  const int b = bh >> 4, h = bh & 15;

  const int q0 = qi * 128 + sub * 32;
  const size_t xbase = (size_t)b * SEQ * DIM + (size_t)h * DH;
  const size_t vtbase = (size_t)bh * DH * SEQ;

  const float SC = 0.125f * 1.44269504089f;  // scale * log2(e)

  // staging ptrs (chunk layout identical to v4)
  const int lc = tid & 511;
  const int srow = lc >> 3;
  const int sw = ((lc & 7) ^ (srow & 7)) * 8;
  const f16* ks0 = kh + xbase + (size_t)srow * DIM + sw;
  const f16* ks1 = kh + xbase + (size_t)(1024 + srow) * DIM + sw;
  const f16* vs0 = vt + vtbase + (size_t)srow * SEQ + sw;
  const f16* vs1 = vt + vtbase + (size_t)srow * SEQ + 1024 + sw;

  auto issue = [&](int buf) {
    f16* B = &KV[buf][wid * 512];
    gll16(ks0, B);
    gll16(vs0, B + 4096);
    gll16(ks1, B + 8192);
    gll16(vs1, B + 12288);
    ks0 += 64 * DIM; ks1 += 64 * DIM; vs0 += 64; vs1 += 64;
  };

  // Q fragments (B-operand)
  half8 qb[4];
  {
    const f16* qrow = qh + xbase + (size_t)(q0 + col) * DIM;
#pragma unroll
    for (int s = 0; s < 4; ++s) qb[s] = *(const half8*)(qrow + s * 16 + hi * 8);
  }

  // static exp2-bound: mexp = ||q|| * max||k|| * scale * log2e
  float mexp;
  {
    float qn2 = 0.f;
#pragma unroll
    for (int s = 0; s < 4; ++s)
#pragma unroll
      for (int jj = 0; jj < 8; ++jj) {
        const float f = (float)qb[s][jj];
        qn2 = fmaf(f, f, qn2);
      }
    qn2 += __shfl_xor(qn2, 32);
    const float kmax = __uint_as_float(kmaxu[bh]);
    mexp = sqrtf(qn2) * kmax * SC;
  }

  f32x16 o0 = {0, 0, 0, 0, 0, 0, 0, 0, 0, 0, 0, 0, 0, 0, 0, 0};
  f32x16 o1 = {0, 0, 0, 0, 0, 0, 0, 0, 0, 0, 0, 0, 0, 0, 0, 0};
  float lsum = 0.f;  // per-lane partial (own hi-half rows); combined at end

  issue(0);

  auto tile = [&](int buf, int t) {
    asm volatile("s_waitcnt vmcnt(0)" ::: "memory");
    __builtin_amdgcn_s_barrier();
    asm volatile("" ::: "memory");
    if (t < 15) issue(buf ^ 1);
    const f16* Ks = &KV[buf][g * 8192];
    const f16* Vs = Ks + 4096;

#pragma unroll
    for (int kvs = 0; kvs < 2; ++kvs) {
      const int krow = kvs * 32 + col;
      f32x16 sacc = {0, 0, 0, 0, 0, 0, 0, 0, 0, 0, 0, 0, 0, 0, 0, 0};
      __builtin_amdgcn_s_setprio(1);
#pragma unroll
      for (int s = 0; s < 4; ++s) {
        const int cc = (2 * s + hi) ^ (krow & 7);
        half8 ka = *(const half8*)&Ks[krow * 64 + cc * 8];
        sacc = __builtin_amdgcn_mfma_f32_32x32x16_f16(ka, qb[s], sacc, 0, 0, 0);
      }
      __builtin_amdgcn_s_setprio(0);

      float pw[16];
#pragma unroll
      for (int r = 0; r < 16; ++r) pw[r] = fexp2(fmaf(sacc[r], SC, -mexp));
      // per-lane tree sum (no cross-lane in loop)
      float s0 = (pw[0] + pw[1]) + (pw[2] + pw[3]);
      float s1 = (pw[4] + pw[5]) + (pw[6] + pw[7]);
      float s2 = (pw[8] + pw[9]) + (pw[10] + pw[11]);
      float s3 = (pw[12] + pw[13]) + (pw[14] + pw[15]);
      lsum += (s0 + s1) + (s2 + s3);

      __builtin_amdgcn_s_setprio(1);
#pragma unroll
      for (int s2i = 0; s2i < 2; ++s2i) {
        const int rb = s2i * 8;
        unsigned X0 = pkrtz(pw[rb + 0], pw[rb + 1]);
        unsigned X1 = pkrtz(pw[rb + 2], pw[rb + 3]);
        unsigned Y0 = pkrtz(pw[rb + 4], pw[rb + 5]);
        unsigned Y1 = pkrtz(pw[rb + 6], pw[rb + 7]);
        pl32swap(X0, Y0);
        pl32swap(X1, Y1);
        const half8 paf = __builtin_bit_cast(half8, (uint4v){X0, X1, Y0, Y1});
        const int kc = kvs * 4 + s2i * 2 + hi;
#pragma unroll
        for (int dt = 0; dt < 2; ++dt) {
          const int vrow = dt * 32 + col;
          const int cc = kc ^ (vrow & 7);
          half8 vb = *(const half8*)&Vs[vrow * 64 + cc * 8];
          if (dt == 0)
            o0 = __builtin_amdgcn_mfma_f32_32x32x16_f16(paf, vb, o0, 0, 0, 0);
          else
            o1 = __builtin_amdgcn_mfma_f32_32x32x16_f16(paf, vb, o1, 0, 0, 0);
        }
      }
      __builtin_amdgcn_s_setprio(0);
    }
  };

  for (int t2 = 0; t2 < 16; t2 += 2) {
    tile(0, t2);
    tile(1, t2 + 1);
  }

  lsum += __shfl_xor(lsum, 32);  // full row-sum for q = col

  // ---- merge the two kv-half partials via LDS (shared static m) ----
  if (g == 1) {
    const float inv = 1.0f / lsum;
    if (hi == 0) { Ll[sub][col] = lsum; bc[wid][col] = inv; }
    f16* po = &KV[0][0] + sub * 2048;  // 32 rows x 64 cols fp16, normalized
#pragma unroll
    for (int r = 0; r < 16; ++r) {
      const int qr = (r & 3) + 8 * (r >> 2) + 4 * hi;
      const float iv = bc[wid][qr];
      po[qr * 64 + col] = (f16)(o0[r] * iv);
      po[qr * 64 + 32 + col] = (f16)(o1[r] * iv);
    }
  }
  __syncthreads();
  if (g == 0) {
    const float l1 = Ll[sub][col];
    const float rden = 1.0f / (lsum + l1);
    const float w1 = l1 * rden;
    if (hi == 0) { W0[sub][col] = rden; W1[sub][col] = w1; }
    const f16* po = &KV[0][0] + sub * 2048;
#pragma unroll
    for (int r = 0; r < 16; ++r) {
      const int qr = (r & 3) + 8 * (r >> 2) + 4 * hi;
      const float c0r = W0[sub][qr], w1r = W1[sub][qr];
      f16* orow = oh + xbase + (size_t)(q0 + qr) * DIM;
      orow[col] = (f16)(c0r * o0[r] + w1r * (float)po[qr * 64 + col]);
      orow[32 + col] = (f16)(c0r * o1[r] + w1r * (float)po[qr * 64 + 32 + col]);
    }
  }
}

extern "C" void kernel_launch(void* const* d_in, const int* in_sizes, int n_in,
                              void* d_out, int out_size, void* d_ws, size_t ws_size,
                              hipStream_t stream)
{
  const float* x  = (const float*)d_in[0];
  const float* Wq = (const float*)d_in[1];
  const float* Wk = (const float*)d_in[2];
  const float* Wv = (const float*)d_in[3];
  const float* Wo = (const float*)d_in[4];
  const float* bo = (const float*)d_in[5];

  char* ws = (char*)d_ws;
  f16* wt   = (f16*)ws;                               // 8 MB
  f16* qkvh = (f16*)(ws + (size_t)8 * 1024 * 1024);   // 24 MB
  f16* ohp  = (f16*)(ws + (size_t)32 * 1024 * 1024);  // 8 MB (aliases xh)
  f16* vtb  = (f16*)(ws + (size_t)40 * 1024 * 1024);  // 8 MB
  f16* xh   = ohp;  // x-fp16 consumed by QKV GEMM before attn writes ohp
  unsigned* kmaxu = (unsigned*)d_out;  // 128 B scratch; final GEMM overwrites

  hipMemsetAsync(kmaxu, 0, 128, stream);

  k_transpose<<<dim3(32, 32, 4), dim3(32, 8), 0, stream>>>(Wq, Wk, Wv, Wo, wt);

  k_xcast<<<2048, 256, 0, stream>>>(x, xh);

  k_gemm2<false><<<dim3(32, 8, 3), 256, 0, stream>>>(
      xh, wt, qkvh, nullptr, MTOT, DIM, DIM,
      (size_t)DIM * DIM, (size_t)MTOT * DIM);

  k_knorm<<<256, 256, 0, stream>>>(qkvh + (size_t)MTOT * DIM, kmaxu);

  k_vtrans<<<dim3(32, 32), 256, 0, stream>>>(
      qkvh + (size_t)2 * MTOT * DIM, vtb);

  k_attn5<<<512, 512, 0, stream>>>(
      qkvh, qkvh + (size_t)MTOT * DIM, vtb, kmaxu, ohp);

  k_gemm2<true><<<dim3(32, 8, 1), 256, 0, stream>>>(
      ohp, wt + (size_t)3 * DIM * DIM, d_out, bo, MTOT, DIM, DIM, 0, 0);
}